// Round 14
// baseline (429.006 us; speedup 1.0000x reference)
//
#include <hip/hip_runtime.h>
#include <math.h>

#define BN   1024
#define NB   32
#define KNN  20
#define NROWS (NB*BN)

typedef __attribute__((ext_vector_type(8))) short bf16x8_t;   // 8 bf16 (4 VGPRs)
typedef __attribute__((ext_vector_type(4))) float f32x4_t;    // MFMA accumulator

__device__ __forceinline__ float finf() { return __builtin_huge_valf(); }

__device__ __forceinline__ unsigned short f2bf(float f) {     // RTNE f32 -> bf16 bits
  union { float f; unsigned u; } v; v.f = f;
  unsigned r = v.u + 0x7FFFu + ((v.u >> 16) & 1u);
  return (unsigned short)(r >> 16);
}
__device__ __forceinline__ float bf2f(unsigned short h) {
  union { unsigned u; float f; } v; v.u = ((unsigned)h) << 16; return v.f;
}

// Monotone float -> uint transform: unsigned order == float order (handles negatives).
__device__ __forceinline__ unsigned fkey(float d) {
  union { float f; unsigned u; } v; v.f = d;
  return (v.u & 0x80000000u) ? ~v.u : (v.u | 0x80000000u);
}

// Emit the 20 smallest: all keys < P (cnt_lt of them), plus the (20-cnt_lt)
// smallest-INDEX members of the boundary bucket {P <= k < P+1024} (bucket members'
// low 10 bits ARE their indices, and t-major emit order == index order).
// Wrap-safe bucket test (kq-P < 1024) covers P near UINT_MAX.
__device__ __forceinline__ void emit20c(const unsigned (&kq)[16], unsigned P, int cnt_lt,
                                        int lane, unsigned short* __restrict__ idx_out) {
  const unsigned long long lmask = (1ull << lane) - 1ull;   // bits strictly below lane
  const int need = KNN - cnt_lt;
  int base_lt = 0, base_eq = 0;
#pragma unroll
  for (int t = 0; t < 16; ++t) {
    const bool lt = (kq[t] < P);
    const bool eq = ((kq[t] - P) < 1024u);
    const unsigned long long mlt = __ballot(lt);
    const unsigned long long meq = __ballot(eq);
    if (lt) idx_out[base_lt + (int)__popcll(mlt & lmask)] = (unsigned short)(kq[t] & 1023u);
    const int erank = base_eq + (int)__popcll(meq & lmask);
    if (eq && erank < need) idx_out[cnt_lt + erank] = (unsigned short)(kq[t] & 1023u);
    base_lt += (int)__popcll(mlt);
    base_eq += (int)__popcll(meq);
  }
}

// Dual-row radix select v2: FIXED 22 iterations over the distance bits [31:10]
// (low 10 bits are the index -- resolved by the capped emit, not the search).
// Branch-free body, both rows every iteration (2 independent ballot streams for ILP;
// round-13 post-mortem: done-flag branches serialized the two chains). Radix
// invariant: final prefix == 20th-smallest key's distance bucket; emit20c completes
// the set with smallest-index bucket members == exact same set/tie-break as before.
__device__ __forceinline__ void select20x2(const unsigned (&k0)[16], const unsigned (&k1)[16],
    int lane, unsigned short* __restrict__ o0, unsigned short* __restrict__ o1) {
  unsigned p0 = 0u, p1 = 0u;
#pragma unroll 1
  for (int b = 31; b >= 10; --b) {
    const unsigned c0 = p0 | (1u << b);
    const unsigned c1 = p1 | (1u << b);
    int n0 = 0, n1 = 0;
#pragma unroll
    for (int t = 0; t < 16; ++t) {
      n0 += (int)__popcll(__ballot(k0[t] < c0));
      n1 += (int)__popcll(__ballot(k1[t] < c1));
    }
    if (n0 < KNN) p0 = c0;        // wave-uniform cselect
    if (n1 < KNN) p1 = c1;
  }
  int c0n = 0, c1n = 0;           // counts strictly below the final prefixes
#pragma unroll
  for (int t = 0; t < 16; ++t) {
    c0n += (int)__popcll(__ballot(k0[t] < p0));
    c1n += (int)__popcll(__ballot(k1[t] < p1));
  }
  emit20c(k0, p0, c0n, lane, o0);
  emit20c(k1, p1, c1n, lane, o1);
}

// ---------------- weight pre-fragmentation: MFMA-ordered bf16 tables ----------------
__global__ __launch_bounds__(256) void prep_kernel(const float* __restrict__ W2, const float* __restrict__ W3,
    const float* __restrict__ W4, const float* __restrict__ Wp,
    unsigned short* __restrict__ w2b, unsigned short* __restrict__ w3b,
    unsigned short* __restrict__ w4b, unsigned short* __restrict__ wpb) {
  const int i = blockIdx.x * 256 + threadIdx.x;
  if (i < 512) {                               // W2
    const int lane = i & 63, ks = (i >> 6) & 1, nt = i >> 7;
    const int col = nt*16 + (lane & 15), k0 = ks*32 + ((lane >> 4) << 3);
#pragma unroll
    for (int e = 0; e < 8; ++e) w2b[i*8 + e] = f2bf(W2[(size_t)(k0 + e)*64 + col]);
  } else if (i < 1024) {                       // W3
    const int ii = i - 512;
    const int lane = ii & 63, ks = (ii >> 6) & 1, nt = ii >> 7;
    const int col = nt*16 + (lane & 15), k0 = ks*32 + ((lane >> 4) << 3);
#pragma unroll
    for (int e = 0; e < 8; ++e) w3b[ii*8 + e] = f2bf(W3[(size_t)(k0 + e)*64 + col]);
  } else if (i < 3072) {                       // W4
    const int ii = i - 1024;
    const int lane = ii & 63, ks = (ii >> 6) & 3, nt = ii >> 8;
    const int col = nt*16 + (lane & 15), k0 = ks*32 + ((lane >> 4) << 3);
#pragma unroll
    for (int e = 0; e < 8; ++e) w4b[ii*8 + e] = f2bf(W4[(size_t)(k0 + e)*128 + col]);
  } else if (i < 11264) {                      // Wp (hi + lo planes)
    const int ii = i - 3072;
    const int lane = ii & 63, ks = (ii >> 6) & 3, nt = ii >> 8;
    const int col = nt*16 + (lane & 15), k0 = ks*32 + ((lane >> 4) << 3);
#pragma unroll
    for (int e = 0; e < 8; ++e) {
      const float v = Wp[(size_t)(k0 + e)*512 + col];
      const unsigned short h = f2bf(v);
      wpb[ii*8 + e]         = h;
      wpb[65536 + ii*8 + e] = f2bf(v - bf2f(h));
    }
  }
}

// ---------------- kNN on 3-D coords: one wave per TWO rows ----------------
__global__ __launch_bounds__(256) void knn3_kernel(const float* __restrict__ x, unsigned short* __restrict__ idxo) {
  const int pair = blockIdx.x * 4 + (threadIdx.x >> 6);
  const int lane = threadIdx.x & 63;
  const int row0 = pair * 2;
  const int b = row0 >> 10;
  const int ia = row0 & (BN - 1), ib = ia + 1;
  const float* xb = x + (size_t)b * BN * 3;
  const float xa0 = xb[ia*3+0], xa1 = xb[ia*3+1], xa2 = xb[ia*3+2];
  const float xb0 = xb[ib*3+0], xb1 = xb[ib*3+1], xb2 = xb[ib*3+2];
  const float sqa = xa0*xa0 + xa1*xa1 + xa2*xa2;
  const float sqb = xb0*xb0 + xb1*xb1 + xb2*xb2;
  unsigned k0[16], k1[16];
#pragma unroll
  for (int t = 0; t < 16; ++t) {
    const int j = (t << 6) | lane;
    const float a0 = xb[j*3+0], a1 = xb[j*3+1], a2 = xb[j*3+2];
    const float sqj = a0*a0 + a1*a1 + a2*a2;
    const float da  = sqa + sqj - 2.0f*(xa0*a0 + xa1*a1 + xa2*a2);   // reference formula
    const float db  = sqb + sqj - 2.0f*(xb0*a0 + xb1*a1 + xb2*a2);
    k0[t] = (j == ia) ? 0xFFFFFFFFu : ((fkey(da) & 0xFFFFFC00u) | (unsigned)j);
    k1[t] = (j == ib) ? 0xFFFFFFFFu : ((fkey(db) & 0xFFFFFC00u) | (unsigned)j);
  }
  select20x2(k0, k1, lane, idxo + (size_t)row0 * KNN, idxo + (size_t)(row0 + 1) * KNN);
}

// ---------------- EdgeConv1 via MFMA, register epilogue (prepped weights) ----------------
__global__ __launch_bounds__(256) void edge1_mfma_kernel(const float* __restrict__ x, const unsigned short* __restrict__ idx,
    const float* __restrict__ W1, const float* __restrict__ B1,
    const unsigned short* __restrict__ w2b, const float* __restrict__ B2,
    const unsigned short* __restrict__ w3b, const float* __restrict__ B3,
    float* __restrict__ out1, unsigned short* __restrict__ hib,
    unsigned short* __restrict__ lob, float* __restrict__ sqbuf) {
  __shared__ unsigned short Hs1[80*64];
  __shared__ unsigned short Hs2[80*64];
  __shared__ float part[4][4];
  const int t = threadIdx.x, lane = t & 63, w = t >> 6;
  const int node0 = blockIdx.x * 4;

  const int bcol = w*16 + (lane & 15);
  bf16x8_t Bf2[2], Bf3[2];
#pragma unroll
  for (int ks = 0; ks < 2; ++ks) {
    Bf2[ks] = *(const bf16x8_t*)&w2b[(size_t)((w*2 + ks)*64 + lane) * 8];
    Bf3[ks] = *(const bf16x8_t*)&w3b[(size_t)((w*2 + ks)*64 + lane) * 8];
  }

  float w1c[6];
#pragma unroll
  for (int c = 0; c < 6; ++c) w1c[c] = W1[c*64 + lane];
  const float b1o = B1[lane];
  for (int r = w; r < 80; r += 4) {
    const int g = (r * 205) >> 12;
    const int e = r - g*20;
    const int node = node0 + g;
    const int b = node >> 10;
    const int j = idx[(size_t)node*KNN + e];
    const float xi0 = x[(size_t)node*3+0], xi1 = x[(size_t)node*3+1], xi2 = x[(size_t)node*3+2];
    const size_t jr = ((size_t)(b*BN + j))*3;
    const float h3 = x[jr+0]-xi0, h4 = x[jr+1]-xi1, h5 = x[jr+2]-xi2;
    float z = b1o + xi0*w1c[0] + xi1*w1c[1] + xi2*w1c[2]
                  + h3*w1c[3] + h4*w1c[4] + h5*w1c[5];
    z = fmaxf(z, 0.0f);
    Hs1[r*64 + (((lane>>3) ^ (r&7))<<3) + (lane&7)] = f2bf(z);
  }
  __syncthreads();

  f32x4_t acc[5];
#pragma unroll
  for (int mt = 0; mt < 5; ++mt) acc[mt] = (f32x4_t){0,0,0,0};
#pragma unroll
  for (int ks = 0; ks < 2; ++ks) {
#pragma unroll
    for (int mt = 0; mt < 5; ++mt) {
      const int r = mt*16 + (lane & 15);
      const int chunk = ks*4 + (lane >> 4);
      const bf16x8_t a = *(const bf16x8_t*)&Hs1[r*64 + ((chunk ^ (r&7))<<3)];
      acc[mt] = __builtin_amdgcn_mfma_f32_16x16x32_bf16(a, Bf2[ks], acc[mt], 0,0,0);
    }
  }
  {
    const float b2o = B2[bcol];
    const int rbase = (lane >> 4) * 4;
#pragma unroll
    for (int mt = 0; mt < 5; ++mt) {
#pragma unroll
      for (int reg = 0; reg < 4; ++reg) {
        const int row = mt*16 + rbase + reg;
        const float v = fmaxf(acc[mt][reg] + b2o, 0.0f);
        Hs2[row*64 + (((bcol>>3) ^ (row&7))<<3) + (bcol&7)] = f2bf(v);
      }
    }
  }
  __syncthreads();

#pragma unroll
  for (int mt = 0; mt < 5; ++mt) acc[mt] = (f32x4_t){0,0,0,0};
#pragma unroll
  for (int ks = 0; ks < 2; ++ks) {
#pragma unroll
    for (int mt = 0; mt < 5; ++mt) {
      const int r = mt*16 + (lane & 15);
      const int chunk = ks*4 + (lane >> 4);
      const bf16x8_t a = *(const bf16x8_t*)&Hs2[r*64 + ((chunk ^ (r&7))<<3)];
      acc[mt] = __builtin_amdgcn_mfma_f32_16x16x32_bf16(a, Bf3[ks], acc[mt], 0,0,0);
    }
  }

  {
    const float b3o = B3[bcol];
    const int rbase = (lane >> 4) * 4;
    float nm0 = 0.0f, nm1 = 0.0f, nm2 = 0.0f, nm3 = 0.0f;
#pragma unroll
    for (int mt = 0; mt < 5; ++mt) {
#pragma unroll
      for (int reg = 0; reg < 4; ++reg) {
        const int r = mt*16 + rbase + reg;
        const int g = (r * 205) >> 12;
        const float v = fmaxf(acc[mt][reg] + b3o, 0.0f);
        nm0 = (g == 0) ? fmaxf(nm0, v) : nm0;
        nm1 = (g == 1) ? fmaxf(nm1, v) : nm1;
        nm2 = (g == 2) ? fmaxf(nm2, v) : nm2;
        nm3 = (g == 3) ? fmaxf(nm3, v) : nm3;
      }
    }
#pragma unroll
    for (int off = 16; off <= 32; off <<= 1) {
      nm0 = fmaxf(nm0, __shfl_xor(nm0, off, 64));
      nm1 = fmaxf(nm1, __shfl_xor(nm1, off, 64));
      nm2 = fmaxf(nm2, __shfl_xor(nm2, off, 64));
      nm3 = fmaxf(nm3, __shfl_xor(nm3, off, 64));
    }
    const int gq = lane >> 4;
    const float m = (gq == 0) ? nm0 : (gq == 1) ? nm1 : (gq == 2) ? nm2 : nm3;
    const int node = node0 + gq;
    out1[(size_t)node*64 + bcol] = m;
    const unsigned short h = f2bf(m);
    hib[(size_t)node*64 + bcol] = h;
    lob[(size_t)node*64 + bcol] = f2bf(m - bf2f(h));
    float s = m * m;
#pragma unroll
    for (int off = 1; off <= 8; off <<= 1) s += __shfl_xor(s, off, 64);
    if ((lane & 15) == 0) part[gq][w] = s;
  }
  __syncthreads();
  if (t < 4) sqbuf[node0 + t] = part[t][0] + part[t][1] + part[t][2] + part[t][3];
}

// ---------------- kNN on 64-d features: bf16x3 MFMA + dual-row radix select ----------------
// 8-row blocks (256 thr, 4 waves): Dmat 32 KB -> 5 blocks/CU (~20 waves, was 12).
// The 16-row MFMA A-tile computes rows 8..15 of the NEIGHBOR block too (discarded) —
// MFMA was 3.8% busy, so half-M waste is cheap; occupancy is the binding constraint.
// acc[4] x 4 phases keeps VGPR near 60 (8 waves/SIMD VGPR class).
__global__ __launch_bounds__(256) void knn64_mfma_kernel(
    const unsigned short* __restrict__ hi, const unsigned short* __restrict__ lo,
    const float* __restrict__ sq, unsigned short* __restrict__ idxo) {
  __shared__ unsigned Dmat[8 * 1024];               // 32 KB packed keys
  const int t = threadIdx.x, lane = t & 63, w = t >> 6;   // w in [0,4)
  const int i0  = blockIdx.x * 8;
  const int b   = i0 >> 10;
  const int i0l = i0 & (BN - 1);

  const int arow_i = min(i0 + (lane & 15), NROWS - 1);   // rows 8..15: neighbor's (discarded)
  const size_t arow = (size_t)arow_i * 64;
  const int koff = (lane >> 4) * 8;
  bf16x8_t Ahi[2], Alo[2];
#pragma unroll
  for (int ks = 0; ks < 2; ++ks) {
    Ahi[ks] = *(const bf16x8_t*)&hi[arow + ks*32 + koff];
    Alo[ks] = *(const bf16x8_t*)&lo[arow + ks*32 + koff];
  }

  const int rbase = (lane >> 4) * 4;
  float sqr[4];
#pragma unroll
  for (int r = 0; r < 4; ++r) sqr[r] = sq[min(i0 + rbase + r, NROWS - 1)];

#pragma unroll 1
  for (int h = 0; h < 4; ++h) {
    f32x4_t acc[4];
#pragma unroll
    for (int nt = 0; nt < 4; ++nt) {
      const int jl = (w*16 + h*4 + nt)*16 + (lane & 15);   // 4 waves x 16 nt = 64 tiles
      const size_t jrow = ((size_t)(b << 10) + jl) * 64;
      const bf16x8_t Bhi0 = *(const bf16x8_t*)&hi[jrow + koff];
      const bf16x8_t Bhi1 = *(const bf16x8_t*)&hi[jrow + 32 + koff];
      const bf16x8_t Blo0 = *(const bf16x8_t*)&lo[jrow + koff];
      const bf16x8_t Blo1 = *(const bf16x8_t*)&lo[jrow + 32 + koff];
      f32x4_t a = (f32x4_t){0,0,0,0};
      a = __builtin_amdgcn_mfma_f32_16x16x32_bf16(Ahi[0], Bhi0, a, 0,0,0);
      a = __builtin_amdgcn_mfma_f32_16x16x32_bf16(Ahi[1], Bhi1, a, 0,0,0);
      a = __builtin_amdgcn_mfma_f32_16x16x32_bf16(Ahi[0], Blo0, a, 0,0,0);
      a = __builtin_amdgcn_mfma_f32_16x16x32_bf16(Ahi[1], Blo1, a, 0,0,0);
      a = __builtin_amdgcn_mfma_f32_16x16x32_bf16(Alo[0], Bhi0, a, 0,0,0);
      a = __builtin_amdgcn_mfma_f32_16x16x32_bf16(Alo[1], Bhi1, a, 0,0,0);
      acc[nt] = a;
    }
    if (rbase < 8) {                                  // keep only this block's 8 rows
#pragma unroll
      for (int nt = 0; nt < 4; ++nt) {
        const int jl = (w*16 + h*4 + nt)*16 + (lane & 15);
        const float sqj = sq[(b << 10) + jl];
#pragma unroll
        for (int r = 0; r < 4; ++r) {
          const float d = sqr[r] + sqj - 2.0f * acc[nt][r];
          const unsigned kq = (jl == i0l + rbase + r) ? 0xFFFFFFFFu
                            : ((fkey(d) & 0xFFFFFC00u) | (unsigned)jl);
          Dmat[(rbase + r)*1024 + jl] = kq;           // 2-way bank (free, m136)
        }
      }
    }
  }
  __syncthreads();

  const int r0 = 2*w, r1 = 2*w + 1;                   // 4 waves x 2 rows = 8 rows
  unsigned k0[16], k1[16];
#pragma unroll
  for (int tt = 0; tt < 16; ++tt) {
    k0[tt] = Dmat[r0*1024 + tt*64 + lane];
    k1[tt] = Dmat[r1*1024 + tt*64 + lane];
  }
  select20x2(k0, k1, lane, idxo + (size_t)(i0 + r0) * KNN, idxo + (size_t)(i0 + r1) * KNN);
}

// ---------------- EdgeConv2: 8 nodes/block, float4 gather, constexpr epilogue ----------------
__global__ __launch_bounds__(256) void edge2_mfma_kernel(const float* __restrict__ f, const unsigned short* __restrict__ idx,
    const unsigned short* __restrict__ w4b, const float* __restrict__ B4,
    unsigned short* __restrict__ o2hi, unsigned short* __restrict__ o2lo) {
  __shared__ unsigned short Hs[160*128];   // 40 KB bf16, swizzled: [r][chunk^(r&7)][0..7]
  const int t = threadIdx.x, lane = t & 63, w = t >> 6;
  const int node0 = blockIdx.x * 8;

  bf16x8_t Bfrag[2][4];
#pragma unroll
  for (int nti = 0; nti < 2; ++nti)
#pragma unroll
    for (int ks = 0; ks < 4; ++ks)
      Bfrag[nti][ks] = *(const bf16x8_t*)&w4b[(size_t)(((2*w + nti)*4 + ks)*64 + lane) * 8];

  const int cq = (lane & 15) * 4;
  const int ch1 = cq >> 3, ch2 = 8 + (cq >> 3), sub = cq & 4;
#pragma unroll 2
  for (int i = 0; i < 10; ++i) {
    const int r = w*40 + i*4 + (lane >> 4);
    const int g = (r * 205) >> 12;          // r/20, exact for r<160
    const int e = r - g*20;
    const int node = node0 + g;
    const int b = node >> 10;
    const int j = idx[(size_t)node*KNN + e];
    const float4 xi = *(const float4*)&f[(size_t)node*64 + cq];
    const float4 xj = *(const float4*)&f[((size_t)(b*BN + j))*64 + cq];
    ushort4 hxi, hdf;
    hxi.x = f2bf(xi.x); hxi.y = f2bf(xi.y); hxi.z = f2bf(xi.z); hxi.w = f2bf(xi.w);
    hdf.x = f2bf(xj.x - xi.x); hdf.y = f2bf(xj.y - xi.y);
    hdf.z = f2bf(xj.z - xi.z); hdf.w = f2bf(xj.w - xi.w);
    *(ushort4*)&Hs[r*128 + ((ch1 ^ (r&7))<<3) + sub] = hxi;
    *(ushort4*)&Hs[r*128 + ((ch2 ^ (r&7))<<3) + sub] = hdf;
  }
  __syncthreads();

  f32x4_t acc[10][2];
#pragma unroll
  for (int mt = 0; mt < 10; ++mt) { acc[mt][0] = (f32x4_t){0,0,0,0}; acc[mt][1] = (f32x4_t){0,0,0,0}; }
#pragma unroll
  for (int ks = 0; ks < 4; ++ks) {
#pragma unroll
    for (int mt = 0; mt < 10; ++mt) {
      const int r = mt*16 + (lane & 15);
      const int chunk = ks*4 + (lane >> 4);
      const bf16x8_t a = *(const bf16x8_t*)&Hs[r*128 + ((chunk ^ (r&7))<<3)];
      acc[mt][0] = __builtin_amdgcn_mfma_f32_16x16x32_bf16(a, Bfrag[0][ks], acc[mt][0], 0,0,0);
      acc[mt][1] = __builtin_amdgcn_mfma_f32_16x16x32_bf16(a, Bfrag[1][ks], acc[mt][1], 0,0,0);
    }
  }

  const float bb0 = B4[(2*w+0)*16 + (lane & 15)];
  const float bb1 = B4[(2*w+1)*16 + (lane & 15)];
  const int rbase = (lane >> 4) * 4;
  float nm[8][2];
#pragma unroll
  for (int g = 0; g < 8; ++g) { nm[g][0] = 0.0f; nm[g][1] = 0.0f; }
#pragma unroll
  for (int mt = 0; mt < 10; ++mt) {
#pragma unroll
    for (int reg = 0; reg < 4; ++reg) {
      const int base = mt*16 + reg;          // compile-time after unroll
      const int glo = base / 20, ghi = (base + 12) / 20;
      const int r = base + rbase;
      const float v0 = fmaxf(acc[mt][0][reg] + bb0, 0.0f);
      const float v1 = fmaxf(acc[mt][1][reg] + bb1, 0.0f);
      if (glo == ghi) {
        nm[glo][0] = fmaxf(nm[glo][0], v0);
        nm[glo][1] = fmaxf(nm[glo][1], v1);
      } else {
        const bool hi = (r >= ghi*20);
        nm[glo][0] = hi ? nm[glo][0] : fmaxf(nm[glo][0], v0);
        nm[glo][1] = hi ? nm[glo][1] : fmaxf(nm[glo][1], v1);
        nm[ghi][0] = hi ? fmaxf(nm[ghi][0], v0) : nm[ghi][0];
        nm[ghi][1] = hi ? fmaxf(nm[ghi][1], v1) : nm[ghi][1];
      }
    }
  }
#pragma unroll
  for (int off = 16; off <= 32; off <<= 1)
#pragma unroll
    for (int g = 0; g < 8; ++g) {
      nm[g][0] = fmaxf(nm[g][0], __shfl_xor(nm[g][0], off, 64));
      nm[g][1] = fmaxf(nm[g][1], __shfl_xor(nm[g][1], off, 64));
    }
  const int gq = lane >> 4;
#pragma unroll
  for (int g = 0; g < 8; ++g) {
    if ((g & 3) == gq) {
#pragma unroll
      for (int nti = 0; nti < 2; ++nti) {
        const float m = nm[g][nti];
        const size_t o = (size_t)(node0 + g)*128 + (2*w + nti)*16 + (lane & 15);
        const unsigned short h = f2bf(m);
        o2hi[o] = h;
        o2lo[o] = f2bf(m - bf2f(h));
      }
    }
  }
}

// ---------------- pool: 128->512 via bf16x3 MFMA, fused relu+max, atomicMax ----------------
__global__ __launch_bounds__(512) void pool_mfma_kernel(const unsigned short* __restrict__ o2hi,
    const unsigned short* __restrict__ o2lo, const unsigned short* __restrict__ wpb,
    const float* __restrict__ bp, float* __restrict__ pooled) {
  const int t = threadIdx.x, lane = t & 63, w = t >> 6;    // 8 waves
  const int b = blockIdx.x >> 3, chunk = blockIdx.x & 7;
  const int row0 = b*BN + chunk*128;
  const int koff = (lane >> 4) * 8;
  bf16x8_t Bhi[4][4], Blo[4][4];
#pragma unroll
  for (int q = 0; q < 4; ++q)
#pragma unroll
    for (int ks = 0; ks < 4; ++ks) {
      const int nt = w*4 + q;
      Bhi[q][ks] = *(const bf16x8_t*)&wpb[(size_t)((nt*4 + ks)*64 + lane) * 8];
      Blo[q][ks] = *(const bf16x8_t*)&wpb[65536 + (size_t)((nt*4 + ks)*64 + lane) * 8];
    }
  float colmax[4] = {-finf(), -finf(), -finf(), -finf()};
#pragma unroll 2
  for (int mt = 0; mt < 8; ++mt) {
    const size_t ar = (size_t)(row0 + mt*16 + (lane & 15)) * 128;
    bf16x8_t Ahi[4], Alo[4];
#pragma unroll
    for (int ks = 0; ks < 4; ++ks) {
      Ahi[ks] = *(const bf16x8_t*)&o2hi[ar + ks*32 + koff];
      Alo[ks] = *(const bf16x8_t*)&o2lo[ar + ks*32 + koff];
    }
#pragma unroll
    for (int q = 0; q < 4; ++q) {
      f32x4_t a = (f32x4_t){0,0,0,0};
#pragma unroll
      for (int ks = 0; ks < 4; ++ks) {
        a = __builtin_amdgcn_mfma_f32_16x16x32_bf16(Ahi[ks], Bhi[q][ks], a, 0,0,0);
        a = __builtin_amdgcn_mfma_f32_16x16x32_bf16(Ahi[ks], Blo[q][ks], a, 0,0,0);
        a = __builtin_amdgcn_mfma_f32_16x16x32_bf16(Alo[ks], Bhi[q][ks], a, 0,0,0);
      }
#pragma unroll
      for (int reg = 0; reg < 4; ++reg) colmax[q] = fmaxf(colmax[q], a[reg]);
    }
  }
#pragma unroll
  for (int off = 16; off <= 32; off <<= 1)
#pragma unroll
    for (int q = 0; q < 4; ++q) colmax[q] = fmaxf(colmax[q], __shfl_xor(colmax[q], off, 64));
  if (lane < 16) {
#pragma unroll
    for (int q = 0; q < 4; ++q) {
      const int col = (w*4 + q)*16 + lane;
      const float m = fmaxf(colmax[q] + bp[col], 0.0f);   // relu(max+b) == max(relu(z))
      atomicMax((int*)(pooled + (size_t)b*512 + col), __float_as_int(m));
    }
  }
}

// ---------------- classifier head 512->256(relu)->40 ----------------
__global__ __launch_bounds__(256) void head_kernel(const float* __restrict__ pooled,
    const float* __restrict__ Wt1, const float* __restrict__ bt1,
    const float* __restrict__ Wt2, const float* __restrict__ bt2,
    float* __restrict__ out) {
  __shared__ float psh[512];
  __shared__ float h1sh[256];
  const int t = threadIdx.x, b = blockIdx.x;
  psh[t]       = pooled[(size_t)b*512 + t];
  psh[t + 256] = pooled[(size_t)b*512 + t + 256];
  __syncthreads();
  float z = bt1[t];
  for (int j = 0; j < 512; ++j) z += psh[j] * Wt1[(size_t)j*256 + t];
  h1sh[t] = fmaxf(z, 0.0f);
  __syncthreads();
  if (t < 40) {
    float z2 = bt2[t];
    for (int j = 0; j < 256; ++j) z2 += h1sh[j] * Wt2[(size_t)j*40 + t];
    out[(size_t)b*40 + t] = z2;
  }
}

extern "C" void kernel_launch(void* const* d_in, const int* in_sizes, int n_in,
                              void* d_out, int out_size, void* d_ws, size_t ws_size,
                              hipStream_t stream) {
  const float* x   = (const float*)d_in[0];
  // d_in[1] = batch indices (unused: equal-sized clouds)
  const float* W1  = (const float*)d_in[2];
  const float* B1  = (const float*)d_in[3];
  const float* W2  = (const float*)d_in[4];
  const float* B2  = (const float*)d_in[5];
  const float* W3  = (const float*)d_in[6];
  const float* B3  = (const float*)d_in[7];
  const float* W4  = (const float*)d_in[8];
  const float* B4  = (const float*)d_in[9];
  const float* Wp  = (const float*)d_in[10];
  const float* bp  = (const float*)d_in[11];
  const float* Wt1 = (const float*)d_in[12];
  const float* bt1 = (const float*)d_in[13];
  const float* Wt2 = (const float*)d_in[14];
  const float* bt2 = (const float*)d_in[15];
  float* out = (float*)d_out;

  // workspace layout (bytes): total 28,295,168 <= proven-available 30,605,312
  char* ws = (char*)d_ws;
  const size_t OFF_SQ     = 0;            // 32768*4            = 131072
  const size_t OFF_IDX1   = 131072;       // 32768*20*2 (u16)   = 1310720
  const size_t OFF_OUT1   = 1441792;      // 32768*64*4         = 8388608
  const size_t OFF_IDX2   = 9830400;      // 32768*20*2 (u16)   = 1310720
  const size_t OFF_X      = 11141120;     // 16 MB: hib/lob (8MB, dead after knn64)
                                          //        then o2hi/o2lo (16MB, edge2->pool)
  const size_t OFF_POOLED = 27918336;     // 32*512*4           = 65536
  const size_t OFF_W2B    = 27983872;     // 4096 u16           = 8192
  const size_t OFF_W3B    = 27992064;     // 4096 u16           = 8192
  const size_t OFF_W4B    = 28000256;     // 16384 u16          = 32768
  const size_t OFF_WPB    = 28033024;     // 131072 u16 (hi+lo) = 262144
  const size_t WS_NEEDED  = 28295168;
  if (ws_size < WS_NEEDED) return;        // fail loudly (validation will catch it)

  float*          sqbuf  = (float*)(ws + OFF_SQ);
  unsigned short* idx1   = (unsigned short*)(ws + OFF_IDX1);
  float*          out1   = (float*)(ws + OFF_OUT1);
  unsigned short* idx2   = (unsigned short*)(ws + OFF_IDX2);
  unsigned short* hib    = (unsigned short*)(ws + OFF_X);
  unsigned short* lob    = (unsigned short*)(ws + OFF_X + 4194304);
  unsigned short* o2hi   = (unsigned short*)(ws + OFF_X);            // overwrites hib/lob
  unsigned short* o2lo   = (unsigned short*)(ws + OFF_X + 8388608);  // after knn64 consumed them
  float*          pooled = (float*)(ws + OFF_POOLED);
  unsigned short* w2b    = (unsigned short*)(ws + OFF_W2B);
  unsigned short* w3b    = (unsigned short*)(ws + OFF_W3B);
  unsigned short* w4b    = (unsigned short*)(ws + OFF_W4B);
  unsigned short* wpb    = (unsigned short*)(ws + OFF_WPB);

  prep_kernel      <<<44,          256, 0, stream>>>(W2, W3, W4, Wp, w2b, w3b, w4b, wpb);
  knn3_kernel      <<<NROWS/8,     256, 0, stream>>>(x, idx1);
  edge1_mfma_kernel<<<NROWS/4,     256, 0, stream>>>(x, idx1, W1, B1, w2b, B2, w3b, B3,
                                                     out1, hib, lob, sqbuf);
  knn64_mfma_kernel<<<NROWS/8,     256, 0, stream>>>(hib, lob, sqbuf, idx2);
  edge2_mfma_kernel<<<NROWS/8,     256, 0, stream>>>(out1, idx2, w4b, B4, o2hi, o2lo);
  hipMemsetAsync(pooled, 0, NB*512*sizeof(float), stream);
  pool_mfma_kernel <<<NB*8,        512, 0, stream>>>(o2hi, o2lo, wpb, bp, pooled);
  head_kernel      <<<NB,          256, 0, stream>>>(pooled, Wt1, bt1, Wt2, bt2, out);
}

// Round 15
// 372.170 us; speedup vs baseline: 1.1527x; 1.1527x over previous
//
#include <hip/hip_runtime.h>
#include <math.h>

#define BN   1024
#define NB   32
#define KNN  20
#define NROWS (NB*BN)

typedef __attribute__((ext_vector_type(8))) short bf16x8_t;   // 8 bf16 (4 VGPRs)
typedef __attribute__((ext_vector_type(4))) float f32x4_t;    // MFMA accumulator

__device__ __forceinline__ float finf() { return __builtin_huge_valf(); }

__device__ __forceinline__ unsigned short f2bf(float f) {     // RTNE f32 -> bf16 bits
  union { float f; unsigned u; } v; v.f = f;
  unsigned r = v.u + 0x7FFFu + ((v.u >> 16) & 1u);
  return (unsigned short)(r >> 16);
}
__device__ __forceinline__ float bf2f(unsigned short h) {
  union { unsigned u; float f; } v; v.u = ((unsigned)h) << 16; return v.f;
}

// Monotone float -> uint transform: unsigned order == float order (handles negatives).
__device__ __forceinline__ unsigned fkey(float d) {
  union { float f; unsigned u; } v; v.f = d;
  return (v.u & 0x80000000u) ? ~v.u : (v.u | 0x80000000u);
}

// Emit indices of all keys <= thr (exactly KNN by construction), arbitrary order.
__device__ __forceinline__ void emit20(const unsigned (&kq)[16], unsigned thr,
                                       int lane, unsigned short* __restrict__ idx_out) {
  const unsigned long long lmask = (1ull << lane) - 1ull;   // bits strictly below lane
  int base = 0;
#pragma unroll
  for (int t = 0; t < 16; ++t) {
    const bool ok = (kq[t] <= thr);
    const unsigned long long m = __ballot(ok);
    if (ok) idx_out[base + (int)__popcll(m & lmask)] = (unsigned short)(kq[t] & 1023u);
    base += (int)__popcll(m);
  }
}

// Boundary-bucket emit (r14-proven): all keys < P (cnt_lt of them) plus the
// (KNN-cnt_lt) smallest-INDEX members of bucket {P <= k < P+1024} (low 10 bits ARE
// the index; t-major emit order == index order). Wrap-safe bucket test.
__device__ __forceinline__ void emit20c(const unsigned (&kq)[16], unsigned P, int cnt_lt,
                                        int lane, unsigned short* __restrict__ idx_out) {
  const unsigned long long lmask = (1ull << lane) - 1ull;
  const int need = KNN - cnt_lt;
  int base_lt = 0, base_eq = 0;
#pragma unroll
  for (int t = 0; t < 16; ++t) {
    const bool lt = (kq[t] < P);
    const bool eq = ((kq[t] - P) < 1024u);
    const unsigned long long mlt = __ballot(lt);
    const unsigned long long meq = __ballot(eq);
    if (lt) idx_out[base_lt + (int)__popcll(mlt & lmask)] = (unsigned short)(kq[t] & 1023u);
    const int erank = base_eq + (int)__popcll(meq & lmask);
    if (eq && erank < need) idx_out[cnt_lt + erank] = (unsigned short)(kq[t] & 1023u);
    base_lt += (int)__popcll(mlt);
    base_eq += (int)__popcll(meq);
  }
}

// Dual-row ballot-radix select (r12/r13-proven structure) with bit-10 cap:
// low 10 key bits are the index -> bits 9..0 are pure tie-break, resolved by
// emit20c's capped bucket emit instead of 10 more serial radix iterations.
// Early exit (cnt==KNN => {k<cand} IS the set) kept — it fired early enough to
// matter in r12/r13. Max 22 iterations (was 32), identical output both paths.
__device__ __forceinline__ void select20x2(const unsigned (&k0)[16], const unsigned (&k1)[16],
    int lane, unsigned short* __restrict__ o0, unsigned short* __restrict__ o1) {
  unsigned p0 = 0u, p1 = 0u;
  bool d0 = false, d1 = false;
#pragma unroll 1
  for (int b = 31; b >= 10; --b) {
    if (!d0) {
      const unsigned cand = p0 | (1u << b);
      int cnt = 0;
#pragma unroll
      for (int t = 0; t < 16; ++t) cnt += (int)__popcll(__ballot(k0[t] < cand));
      if (cnt == KNN)      { p0 = cand - 1u; d0 = true; }   // exact set: {k <= cand-1}
      else if (cnt < KNN)  { p0 = cand; }
    }
    if (!d1) {
      const unsigned cand = p1 | (1u << b);
      int cnt = 0;
#pragma unroll
      for (int t = 0; t < 16; ++t) cnt += (int)__popcll(__ballot(k1[t] < cand));
      if (cnt == KNN)      { p1 = cand - 1u; d1 = true; }
      else if (cnt < KNN)  { p1 = cand; }
    }
    if (d0 && d1) break;
  }
  if (d0) emit20(k0, p0, lane, o0);
  else {                                   // p0 = 20th key's 1024-bucket prefix
    int c = 0;
#pragma unroll
    for (int t = 0; t < 16; ++t) c += (int)__popcll(__ballot(k0[t] < p0));
    emit20c(k0, p0, c, lane, o0);
  }
  if (d1) emit20(k1, p1, lane, o1);
  else {
    int c = 0;
#pragma unroll
    for (int t = 0; t < 16; ++t) c += (int)__popcll(__ballot(k1[t] < p1));
    emit20c(k1, p1, c, lane, o1);
  }
}

// ---------------- weight pre-fragmentation: MFMA-ordered bf16 tables ----------------
__global__ __launch_bounds__(256) void prep_kernel(const float* __restrict__ W2, const float* __restrict__ W3,
    const float* __restrict__ W4, const float* __restrict__ Wp,
    unsigned short* __restrict__ w2b, unsigned short* __restrict__ w3b,
    unsigned short* __restrict__ w4b, unsigned short* __restrict__ wpb) {
  const int i = blockIdx.x * 256 + threadIdx.x;
  if (i < 512) {                               // W2
    const int lane = i & 63, ks = (i >> 6) & 1, nt = i >> 7;
    const int col = nt*16 + (lane & 15), k0 = ks*32 + ((lane >> 4) << 3);
#pragma unroll
    for (int e = 0; e < 8; ++e) w2b[i*8 + e] = f2bf(W2[(size_t)(k0 + e)*64 + col]);
  } else if (i < 1024) {                       // W3
    const int ii = i - 512;
    const int lane = ii & 63, ks = (ii >> 6) & 1, nt = ii >> 7;
    const int col = nt*16 + (lane & 15), k0 = ks*32 + ((lane >> 4) << 3);
#pragma unroll
    for (int e = 0; e < 8; ++e) w3b[ii*8 + e] = f2bf(W3[(size_t)(k0 + e)*64 + col]);
  } else if (i < 3072) {                       // W4
    const int ii = i - 1024;
    const int lane = ii & 63, ks = (ii >> 6) & 3, nt = ii >> 8;
    const int col = nt*16 + (lane & 15), k0 = ks*32 + ((lane >> 4) << 3);
#pragma unroll
    for (int e = 0; e < 8; ++e) w4b[ii*8 + e] = f2bf(W4[(size_t)(k0 + e)*128 + col]);
  } else if (i < 11264) {                      // Wp (hi + lo planes)
    const int ii = i - 3072;
    const int lane = ii & 63, ks = (ii >> 6) & 3, nt = ii >> 8;
    const int col = nt*16 + (lane & 15), k0 = ks*32 + ((lane >> 4) << 3);
#pragma unroll
    for (int e = 0; e < 8; ++e) {
      const float v = Wp[(size_t)(k0 + e)*512 + col];
      const unsigned short h = f2bf(v);
      wpb[ii*8 + e]         = h;
      wpb[65536 + ii*8 + e] = f2bf(v - bf2f(h));
    }
  }
}

// ---------------- kNN on 3-D coords: one wave per TWO rows ----------------
__global__ __launch_bounds__(256) void knn3_kernel(const float* __restrict__ x, unsigned short* __restrict__ idxo) {
  const int pair = blockIdx.x * 4 + (threadIdx.x >> 6);
  const int lane = threadIdx.x & 63;
  const int row0 = pair * 2;
  const int b = row0 >> 10;
  const int ia = row0 & (BN - 1), ib = ia + 1;
  const float* xb = x + (size_t)b * BN * 3;
  const float xa0 = xb[ia*3+0], xa1 = xb[ia*3+1], xa2 = xb[ia*3+2];
  const float xb0 = xb[ib*3+0], xb1 = xb[ib*3+1], xb2 = xb[ib*3+2];
  const float sqa = xa0*xa0 + xa1*xa1 + xa2*xa2;
  const float sqb = xb0*xb0 + xb1*xb1 + xb2*xb2;
  unsigned k0[16], k1[16];
#pragma unroll
  for (int t = 0; t < 16; ++t) {
    const int j = (t << 6) | lane;
    const float a0 = xb[j*3+0], a1 = xb[j*3+1], a2 = xb[j*3+2];
    const float sqj = a0*a0 + a1*a1 + a2*a2;
    const float da  = sqa + sqj - 2.0f*(xa0*a0 + xa1*a1 + xa2*a2);   // reference formula
    const float db  = sqb + sqj - 2.0f*(xb0*a0 + xb1*a1 + xb2*a2);
    k0[t] = (j == ia) ? 0xFFFFFFFFu : ((fkey(da) & 0xFFFFFC00u) | (unsigned)j);
    k1[t] = (j == ib) ? 0xFFFFFFFFu : ((fkey(db) & 0xFFFFFC00u) | (unsigned)j);
  }
  select20x2(k0, k1, lane, idxo + (size_t)row0 * KNN, idxo + (size_t)(row0 + 1) * KNN);
}

// ---------------- EdgeConv1 via MFMA, register epilogue (prepped weights) ----------------
__global__ __launch_bounds__(256) void edge1_mfma_kernel(const float* __restrict__ x, const unsigned short* __restrict__ idx,
    const float* __restrict__ W1, const float* __restrict__ B1,
    const unsigned short* __restrict__ w2b, const float* __restrict__ B2,
    const unsigned short* __restrict__ w3b, const float* __restrict__ B3,
    float* __restrict__ out1, unsigned short* __restrict__ hib,
    unsigned short* __restrict__ lob, float* __restrict__ sqbuf) {
  __shared__ unsigned short Hs1[80*64];
  __shared__ unsigned short Hs2[80*64];
  __shared__ float part[4][4];
  const int t = threadIdx.x, lane = t & 63, w = t >> 6;
  const int node0 = blockIdx.x * 4;

  const int bcol = w*16 + (lane & 15);
  bf16x8_t Bf2[2], Bf3[2];
#pragma unroll
  for (int ks = 0; ks < 2; ++ks) {
    Bf2[ks] = *(const bf16x8_t*)&w2b[(size_t)((w*2 + ks)*64 + lane) * 8];
    Bf3[ks] = *(const bf16x8_t*)&w3b[(size_t)((w*2 + ks)*64 + lane) * 8];
  }

  float w1c[6];
#pragma unroll
  for (int c = 0; c < 6; ++c) w1c[c] = W1[c*64 + lane];
  const float b1o = B1[lane];
  for (int r = w; r < 80; r += 4) {
    const int g = (r * 205) >> 12;
    const int e = r - g*20;
    const int node = node0 + g;
    const int b = node >> 10;
    const int j = idx[(size_t)node*KNN + e];
    const float xi0 = x[(size_t)node*3+0], xi1 = x[(size_t)node*3+1], xi2 = x[(size_t)node*3+2];
    const size_t jr = ((size_t)(b*BN + j))*3;
    const float h3 = x[jr+0]-xi0, h4 = x[jr+1]-xi1, h5 = x[jr+2]-xi2;
    float z = b1o + xi0*w1c[0] + xi1*w1c[1] + xi2*w1c[2]
                  + h3*w1c[3] + h4*w1c[4] + h5*w1c[5];
    z = fmaxf(z, 0.0f);
    Hs1[r*64 + (((lane>>3) ^ (r&7))<<3) + (lane&7)] = f2bf(z);
  }
  __syncthreads();

  f32x4_t acc[5];
#pragma unroll
  for (int mt = 0; mt < 5; ++mt) acc[mt] = (f32x4_t){0,0,0,0};
#pragma unroll
  for (int ks = 0; ks < 2; ++ks) {
#pragma unroll
    for (int mt = 0; mt < 5; ++mt) {
      const int r = mt*16 + (lane & 15);
      const int chunk = ks*4 + (lane >> 4);
      const bf16x8_t a = *(const bf16x8_t*)&Hs1[r*64 + ((chunk ^ (r&7))<<3)];
      acc[mt] = __builtin_amdgcn_mfma_f32_16x16x32_bf16(a, Bf2[ks], acc[mt], 0,0,0);
    }
  }
  {
    const float b2o = B2[bcol];
    const int rbase = (lane >> 4) * 4;
#pragma unroll
    for (int mt = 0; mt < 5; ++mt) {
#pragma unroll
      for (int reg = 0; reg < 4; ++reg) {
        const int row = mt*16 + rbase + reg;
        const float v = fmaxf(acc[mt][reg] + b2o, 0.0f);
        Hs2[row*64 + (((bcol>>3) ^ (row&7))<<3) + (bcol&7)] = f2bf(v);
      }
    }
  }
  __syncthreads();

#pragma unroll
  for (int mt = 0; mt < 5; ++mt) acc[mt] = (f32x4_t){0,0,0,0};
#pragma unroll
  for (int ks = 0; ks < 2; ++ks) {
#pragma unroll
    for (int mt = 0; mt < 5; ++mt) {
      const int r = mt*16 + (lane & 15);
      const int chunk = ks*4 + (lane >> 4);
      const bf16x8_t a = *(const bf16x8_t*)&Hs2[r*64 + ((chunk ^ (r&7))<<3)];
      acc[mt] = __builtin_amdgcn_mfma_f32_16x16x32_bf16(a, Bf3[ks], acc[mt], 0,0,0);
    }
  }

  {
    const float b3o = B3[bcol];
    const int rbase = (lane >> 4) * 4;
    float nm0 = 0.0f, nm1 = 0.0f, nm2 = 0.0f, nm3 = 0.0f;
#pragma unroll
    for (int mt = 0; mt < 5; ++mt) {
#pragma unroll
      for (int reg = 0; reg < 4; ++reg) {
        const int r = mt*16 + rbase + reg;
        const int g = (r * 205) >> 12;
        const float v = fmaxf(acc[mt][reg] + b3o, 0.0f);
        nm0 = (g == 0) ? fmaxf(nm0, v) : nm0;
        nm1 = (g == 1) ? fmaxf(nm1, v) : nm1;
        nm2 = (g == 2) ? fmaxf(nm2, v) : nm2;
        nm3 = (g == 3) ? fmaxf(nm3, v) : nm3;
      }
    }
#pragma unroll
    for (int off = 16; off <= 32; off <<= 1) {
      nm0 = fmaxf(nm0, __shfl_xor(nm0, off, 64));
      nm1 = fmaxf(nm1, __shfl_xor(nm1, off, 64));
      nm2 = fmaxf(nm2, __shfl_xor(nm2, off, 64));
      nm3 = fmaxf(nm3, __shfl_xor(nm3, off, 64));
    }
    const int gq = lane >> 4;
    const float m = (gq == 0) ? nm0 : (gq == 1) ? nm1 : (gq == 2) ? nm2 : nm3;
    const int node = node0 + gq;
    out1[(size_t)node*64 + bcol] = m;
    const unsigned short h = f2bf(m);
    hib[(size_t)node*64 + bcol] = h;
    lob[(size_t)node*64 + bcol] = f2bf(m - bf2f(h));
    float s = m * m;
#pragma unroll
    for (int off = 1; off <= 8; off <<= 1) s += __shfl_xor(s, off, 64);
    if ((lane & 15) == 0) part[gq][w] = s;
  }
  __syncthreads();
  if (t < 4) sqbuf[node0 + t] = part[t][0] + part[t][1] + part[t][2] + part[t][3];
}

// ---------------- kNN on 64-d features: bf16x3 MFMA + dual-row radix select ----------------
// ROUND-13 STRUCTURE (125 µs measured): 8 waves (512 thr) per 16 rows; wave w computes
// 8 n-tiles of D, then selects rows {2w,2w+1}. r14's 8-row variant regressed (180 µs):
// occupancy did not improve and MFMA work doubled — reverted.
__global__ __launch_bounds__(512) void knn64_mfma_kernel(
    const unsigned short* __restrict__ hi, const unsigned short* __restrict__ lo,
    const float* __restrict__ sq, unsigned short* __restrict__ idxo) {
  __shared__ unsigned Dmat[16 * 1024];              // 64 KiB packed keys
  const int t = threadIdx.x, lane = t & 63, w = t >> 6;   // w in [0,8)
  const int i0  = blockIdx.x * 16;
  const int b   = i0 >> 10;
  const int i0l = i0 & (BN - 1);

  const size_t arow = (size_t)(i0 + (lane & 15)) * 64;
  const int    koff = (lane >> 4) * 8;
  bf16x8_t Ahi[2], Alo[2];
#pragma unroll
  for (int ks = 0; ks < 2; ++ks) {
    Ahi[ks] = *(const bf16x8_t*)&hi[arow + ks*32 + koff];
    Alo[ks] = *(const bf16x8_t*)&lo[arow + ks*32 + koff];
  }

  f32x4_t acc[8];
#pragma unroll
  for (int nt = 0; nt < 8; ++nt) {
    const int jl = (8*w + nt)*16 + (lane & 15);
    const size_t jrow = ((size_t)(b << 10) + jl) * 64;
    const bf16x8_t Bhi0 = *(const bf16x8_t*)&hi[jrow + koff];
    const bf16x8_t Bhi1 = *(const bf16x8_t*)&hi[jrow + 32 + koff];
    const bf16x8_t Blo0 = *(const bf16x8_t*)&lo[jrow + koff];
    const bf16x8_t Blo1 = *(const bf16x8_t*)&lo[jrow + 32 + koff];
    f32x4_t a = (f32x4_t){0,0,0,0};
    a = __builtin_amdgcn_mfma_f32_16x16x32_bf16(Ahi[0], Bhi0, a, 0,0,0);
    a = __builtin_amdgcn_mfma_f32_16x16x32_bf16(Ahi[1], Bhi1, a, 0,0,0);
    a = __builtin_amdgcn_mfma_f32_16x16x32_bf16(Ahi[0], Blo0, a, 0,0,0);
    a = __builtin_amdgcn_mfma_f32_16x16x32_bf16(Ahi[1], Blo1, a, 0,0,0);
    a = __builtin_amdgcn_mfma_f32_16x16x32_bf16(Alo[0], Bhi0, a, 0,0,0);
    a = __builtin_amdgcn_mfma_f32_16x16x32_bf16(Alo[1], Bhi1, a, 0,0,0);
    acc[nt] = a;
  }

  const int rbase = (lane >> 4) * 4;
  float sqr[4];
#pragma unroll
  for (int r = 0; r < 4; ++r) sqr[r] = sq[i0 + rbase + r];
#pragma unroll
  for (int nt = 0; nt < 8; ++nt) {
    const int jl = (8*w + nt)*16 + (lane & 15);
    const float sqj = sq[(b << 10) + jl];
#pragma unroll
    for (int r = 0; r < 4; ++r) {
      const float d = sqr[r] + sqj - 2.0f * acc[nt][r];
      const unsigned kq = (jl == i0l + rbase + r) ? 0xFFFFFFFFu
                        : ((fkey(d) & 0xFFFFFC00u) | (unsigned)jl);
      Dmat[(rbase + r)*1024 + jl] = kq;
    }
  }
  __syncthreads();

  const int r0 = 2*w, r1 = 2*w + 1;
  unsigned k0[16], k1[16];
#pragma unroll
  for (int tt = 0; tt < 16; ++tt) {
    k0[tt] = Dmat[r0*1024 + tt*64 + lane];
    k1[tt] = Dmat[r1*1024 + tt*64 + lane];
  }
  select20x2(k0, k1, lane, idxo + (size_t)(i0 + r0) * KNN, idxo + (size_t)(i0 + r1) * KNN);
}

// ---------------- EdgeConv2: 8 nodes/block, float4 gather, constexpr epilogue ----------------
__global__ __launch_bounds__(256) void edge2_mfma_kernel(const float* __restrict__ f, const unsigned short* __restrict__ idx,
    const unsigned short* __restrict__ w4b, const float* __restrict__ B4,
    unsigned short* __restrict__ o2hi, unsigned short* __restrict__ o2lo) {
  __shared__ unsigned short Hs[160*128];   // 40 KB bf16, swizzled: [r][chunk^(r&7)][0..7]
  const int t = threadIdx.x, lane = t & 63, w = t >> 6;
  const int node0 = blockIdx.x * 8;

  bf16x8_t Bfrag[2][4];
#pragma unroll
  for (int nti = 0; nti < 2; ++nti)
#pragma unroll
    for (int ks = 0; ks < 4; ++ks)
      Bfrag[nti][ks] = *(const bf16x8_t*)&w4b[(size_t)(((2*w + nti)*4 + ks)*64 + lane) * 8];

  const int cq = (lane & 15) * 4;
  const int ch1 = cq >> 3, ch2 = 8 + (cq >> 3), sub = cq & 4;
#pragma unroll 2
  for (int i = 0; i < 10; ++i) {
    const int r = w*40 + i*4 + (lane >> 4);
    const int g = (r * 205) >> 12;          // r/20, exact for r<160
    const int e = r - g*20;
    const int node = node0 + g;
    const int b = node >> 10;
    const int j = idx[(size_t)node*KNN + e];
    const float4 xi = *(const float4*)&f[(size_t)node*64 + cq];
    const float4 xj = *(const float4*)&f[((size_t)(b*BN + j))*64 + cq];
    ushort4 hxi, hdf;
    hxi.x = f2bf(xi.x); hxi.y = f2bf(xi.y); hxi.z = f2bf(xi.z); hxi.w = f2bf(xi.w);
    hdf.x = f2bf(xj.x - xi.x); hdf.y = f2bf(xj.y - xi.y);
    hdf.z = f2bf(xj.z - xi.z); hdf.w = f2bf(xj.w - xi.w);
    *(ushort4*)&Hs[r*128 + ((ch1 ^ (r&7))<<3) + sub] = hxi;
    *(ushort4*)&Hs[r*128 + ((ch2 ^ (r&7))<<3) + sub] = hdf;
  }
  __syncthreads();

  f32x4_t acc[10][2];
#pragma unroll
  for (int mt = 0; mt < 10; ++mt) { acc[mt][0] = (f32x4_t){0,0,0,0}; acc[mt][1] = (f32x4_t){0,0,0,0}; }
#pragma unroll
  for (int ks = 0; ks < 4; ++ks) {
#pragma unroll
    for (int mt = 0; mt < 10; ++mt) {
      const int r = mt*16 + (lane & 15);
      const int chunk = ks*4 + (lane >> 4);
      const bf16x8_t a = *(const bf16x8_t*)&Hs[r*128 + ((chunk ^ (r&7))<<3)];
      acc[mt][0] = __builtin_amdgcn_mfma_f32_16x16x32_bf16(a, Bfrag[0][ks], acc[mt][0], 0,0,0);
      acc[mt][1] = __builtin_amdgcn_mfma_f32_16x16x32_bf16(a, Bfrag[1][ks], acc[mt][1], 0,0,0);
    }
  }

  const float bb0 = B4[(2*w+0)*16 + (lane & 15)];
  const float bb1 = B4[(2*w+1)*16 + (lane & 15)];
  const int rbase = (lane >> 4) * 4;
  float nm[8][2];
#pragma unroll
  for (int g = 0; g < 8; ++g) { nm[g][0] = 0.0f; nm[g][1] = 0.0f; }
#pragma unroll
  for (int mt = 0; mt < 10; ++mt) {
#pragma unroll
    for (int reg = 0; reg < 4; ++reg) {
      const int base = mt*16 + reg;          // compile-time after unroll
      const int glo = base / 20, ghi = (base + 12) / 20;
      const int r = base + rbase;
      const float v0 = fmaxf(acc[mt][0][reg] + bb0, 0.0f);
      const float v1 = fmaxf(acc[mt][1][reg] + bb1, 0.0f);
      if (glo == ghi) {
        nm[glo][0] = fmaxf(nm[glo][0], v0);
        nm[glo][1] = fmaxf(nm[glo][1], v1);
      } else {
        const bool hi = (r >= ghi*20);
        nm[glo][0] = hi ? nm[glo][0] : fmaxf(nm[glo][0], v0);
        nm[glo][1] = hi ? nm[glo][1] : fmaxf(nm[glo][1], v1);
        nm[ghi][0] = hi ? fmaxf(nm[ghi][0], v0) : nm[ghi][0];
        nm[ghi][1] = hi ? fmaxf(nm[ghi][1], v1) : nm[ghi][1];
      }
    }
  }
#pragma unroll
  for (int off = 16; off <= 32; off <<= 1)
#pragma unroll
    for (int g = 0; g < 8; ++g) {
      nm[g][0] = fmaxf(nm[g][0], __shfl_xor(nm[g][0], off, 64));
      nm[g][1] = fmaxf(nm[g][1], __shfl_xor(nm[g][1], off, 64));
    }
  const int gq = lane >> 4;
#pragma unroll
  for (int g = 0; g < 8; ++g) {
    if ((g & 3) == gq) {
#pragma unroll
      for (int nti = 0; nti < 2; ++nti) {
        const float m = nm[g][nti];
        const size_t o = (size_t)(node0 + g)*128 + (2*w + nti)*16 + (lane & 15);
        const unsigned short h = f2bf(m);
        o2hi[o] = h;
        o2lo[o] = f2bf(m - bf2f(h));
      }
    }
  }
}

// ---------------- pool: 128->512 via bf16x3 MFMA, fused relu+max, atomicMax ----------------
__global__ __launch_bounds__(512) void pool_mfma_kernel(const unsigned short* __restrict__ o2hi,
    const unsigned short* __restrict__ o2lo, const unsigned short* __restrict__ wpb,
    const float* __restrict__ bp, float* __restrict__ pooled) {
  const int t = threadIdx.x, lane = t & 63, w = t >> 6;    // 8 waves
  const int b = blockIdx.x >> 3, chunk = blockIdx.x & 7;
  const int row0 = b*BN + chunk*128;
  const int koff = (lane >> 4) * 8;
  bf16x8_t Bhi[4][4], Blo[4][4];
#pragma unroll
  for (int q = 0; q < 4; ++q)
#pragma unroll
    for (int ks = 0; ks < 4; ++ks) {
      const int nt = w*4 + q;
      Bhi[q][ks] = *(const bf16x8_t*)&wpb[(size_t)((nt*4 + ks)*64 + lane) * 8];
      Blo[q][ks] = *(const bf16x8_t*)&wpb[65536 + (size_t)((nt*4 + ks)*64 + lane) * 8];
    }
  float colmax[4] = {-finf(), -finf(), -finf(), -finf()};
#pragma unroll 2
  for (int mt = 0; mt < 8; ++mt) {
    const size_t ar = (size_t)(row0 + mt*16 + (lane & 15)) * 128;
    bf16x8_t Ahi[4], Alo[4];
#pragma unroll
    for (int ks = 0; ks < 4; ++ks) {
      Ahi[ks] = *(const bf16x8_t*)&o2hi[ar + ks*32 + koff];
      Alo[ks] = *(const bf16x8_t*)&o2lo[ar + ks*32 + koff];
    }
#pragma unroll
    for (int q = 0; q < 4; ++q) {
      f32x4_t a = (f32x4_t){0,0,0,0};
#pragma unroll
      for (int ks = 0; ks < 4; ++ks) {
        a = __builtin_amdgcn_mfma_f32_16x16x32_bf16(Ahi[ks], Bhi[q][ks], a, 0,0,0);
        a = __builtin_amdgcn_mfma_f32_16x16x32_bf16(Ahi[ks], Blo[q][ks], a, 0,0,0);
        a = __builtin_amdgcn_mfma_f32_16x16x32_bf16(Alo[ks], Bhi[q][ks], a, 0,0,0);
      }
#pragma unroll
      for (int reg = 0; reg < 4; ++reg) colmax[q] = fmaxf(colmax[q], a[reg]);
    }
  }
#pragma unroll
  for (int off = 16; off <= 32; off <<= 1)
#pragma unroll
    for (int q = 0; q < 4; ++q) colmax[q] = fmaxf(colmax[q], __shfl_xor(colmax[q], off, 64));
  if (lane < 16) {
#pragma unroll
    for (int q = 0; q < 4; ++q) {
      const int col = (w*4 + q)*16 + lane;
      const float m = fmaxf(colmax[q] + bp[col], 0.0f);   // relu(max+b) == max(relu(z))
      atomicMax((int*)(pooled + (size_t)b*512 + col), __float_as_int(m));
    }
  }
}

// ---------------- classifier head 512->256(relu)->40 ----------------
__global__ __launch_bounds__(256) void head_kernel(const float* __restrict__ pooled,
    const float* __restrict__ Wt1, const float* __restrict__ bt1,
    const float* __restrict__ Wt2, const float* __restrict__ bt2,
    float* __restrict__ out) {
  __shared__ float psh[512];
  __shared__ float h1sh[256];
  const int t = threadIdx.x, b = blockIdx.x;
  psh[t]       = pooled[(size_t)b*512 + t];
  psh[t + 256] = pooled[(size_t)b*512 + t + 256];
  __syncthreads();
  float z = bt1[t];
  for (int j = 0; j < 512; ++j) z += psh[j] * Wt1[(size_t)j*256 + t];
  h1sh[t] = fmaxf(z, 0.0f);
  __syncthreads();
  if (t < 40) {
    float z2 = bt2[t];
    for (int j = 0; j < 256; ++j) z2 += h1sh[j] * Wt2[(size_t)j*40 + t];
    out[(size_t)b*40 + t] = z2;
  }
}

extern "C" void kernel_launch(void* const* d_in, const int* in_sizes, int n_in,
                              void* d_out, int out_size, void* d_ws, size_t ws_size,
                              hipStream_t stream) {
  const float* x   = (const float*)d_in[0];
  // d_in[1] = batch indices (unused: equal-sized clouds)
  const float* W1  = (const float*)d_in[2];
  const float* B1  = (const float*)d_in[3];
  const float* W2  = (const float*)d_in[4];
  const float* B2  = (const float*)d_in[5];
  const float* W3  = (const float*)d_in[6];
  const float* B3  = (const float*)d_in[7];
  const float* W4  = (const float*)d_in[8];
  const float* B4  = (const float*)d_in[9];
  const float* Wp  = (const float*)d_in[10];
  const float* bp  = (const float*)d_in[11];
  const float* Wt1 = (const float*)d_in[12];
  const float* bt1 = (const float*)d_in[13];
  const float* Wt2 = (const float*)d_in[14];
  const float* bt2 = (const float*)d_in[15];
  float* out = (float*)d_out;

  // workspace layout (bytes): total 28,295,168 <= proven-available 30,605,312
  char* ws = (char*)d_ws;
  const size_t OFF_SQ     = 0;            // 32768*4            = 131072
  const size_t OFF_IDX1   = 131072;       // 32768*20*2 (u16)   = 1310720
  const size_t OFF_OUT1   = 1441792;      // 32768*64*4         = 8388608
  const size_t OFF_IDX2   = 9830400;      // 32768*20*2 (u16)   = 1310720
  const size_t OFF_X      = 11141120;     // 16 MB: hib/lob (8MB, dead after knn64)
                                          //        then o2hi/o2lo (16MB, edge2->pool)
  const size_t OFF_POOLED = 27918336;     // 32*512*4           = 65536
  const size_t OFF_W2B    = 27983872;     // 4096 u16           = 8192
  const size_t OFF_W3B    = 27992064;     // 4096 u16           = 8192
  const size_t OFF_W4B    = 28000256;     // 16384 u16          = 32768
  const size_t OFF_WPB    = 28033024;     // 131072 u16 (hi+lo) = 262144
  const size_t WS_NEEDED  = 28295168;
  if (ws_size < WS_NEEDED) return;        // fail loudly (validation will catch it)

  float*          sqbuf  = (float*)(ws + OFF_SQ);
  unsigned short* idx1   = (unsigned short*)(ws + OFF_IDX1);
  float*          out1   = (float*)(ws + OFF_OUT1);
  unsigned short* idx2   = (unsigned short*)(ws + OFF_IDX2);
  unsigned short* hib    = (unsigned short*)(ws + OFF_X);
  unsigned short* lob    = (unsigned short*)(ws + OFF_X + 4194304);
  unsigned short* o2hi   = (unsigned short*)(ws + OFF_X);            // overwrites hib/lob
  unsigned short* o2lo   = (unsigned short*)(ws + OFF_X + 8388608);  // after knn64 consumed them
  float*          pooled = (float*)(ws + OFF_POOLED);
  unsigned short* w2b    = (unsigned short*)(ws + OFF_W2B);
  unsigned short* w3b    = (unsigned short*)(ws + OFF_W3B);
  unsigned short* w4b    = (unsigned short*)(ws + OFF_W4B);
  unsigned short* wpb    = (unsigned short*)(ws + OFF_WPB);

  prep_kernel      <<<44,          256, 0, stream>>>(W2, W3, W4, Wp, w2b, w3b, w4b, wpb);
  knn3_kernel      <<<NROWS/8,     256, 0, stream>>>(x, idx1);
  edge1_mfma_kernel<<<NROWS/4,     256, 0, stream>>>(x, idx1, W1, B1, w2b, B2, w3b, B3,
                                                     out1, hib, lob, sqbuf);
  knn64_mfma_kernel<<<NROWS/16,    512, 0, stream>>>(hib, lob, sqbuf, idx2);
  edge2_mfma_kernel<<<NROWS/8,     256, 0, stream>>>(out1, idx2, w4b, B4, o2hi, o2lo);
  hipMemsetAsync(pooled, 0, NB*512*sizeof(float), stream);
  pool_mfma_kernel <<<NB*8,        512, 0, stream>>>(o2hi, o2lo, wpb, bp, pooled);
  head_kernel      <<<NB,          256, 0, stream>>>(pooled, Wt1, bt1, Wt2, bt2, out);
}

// Round 16
// 332.606 us; speedup vs baseline: 1.2898x; 1.1190x over previous
//
#include <hip/hip_runtime.h>
#include <math.h>

#define BN   1024
#define NB   32
#define KNN  20
#define NROWS (NB*BN)

typedef __attribute__((ext_vector_type(8))) short bf16x8_t;   // 8 bf16 (4 VGPRs)
typedef __attribute__((ext_vector_type(4))) float f32x4_t;    // MFMA accumulator

__device__ __forceinline__ float finf() { return __builtin_huge_valf(); }

__device__ __forceinline__ unsigned short f2bf(float f) {     // RTNE f32 -> bf16 bits
  union { float f; unsigned u; } v; v.f = f;
  unsigned r = v.u + 0x7FFFu + ((v.u >> 16) & 1u);
  return (unsigned short)(r >> 16);
}
__device__ __forceinline__ float bf2f(unsigned short h) {
  union { unsigned u; float f; } v; v.u = ((unsigned)h) << 16; return v.f;
}

// Monotone float -> uint transform: unsigned order == float order (handles negatives).
__device__ __forceinline__ unsigned fkey(float d) {
  union { float f; unsigned u; } v; v.f = d;
  return (v.u & 0x80000000u) ? ~v.u : (v.u | 0x80000000u);
}

// Emit indices of all keys <= thr (exactly KNN by construction), arbitrary order.
__device__ __forceinline__ void emit20(const unsigned (&kq)[16], unsigned thr,
                                       int lane, unsigned short* __restrict__ idx_out) {
  const unsigned long long lmask = (1ull << lane) - 1ull;   // bits strictly below lane
  int base = 0;
#pragma unroll
  for (int t = 0; t < 16; ++t) {
    const bool ok = (kq[t] <= thr);
    const unsigned long long m = __ballot(ok);
    if (ok) idx_out[base + (int)__popcll(m & lmask)] = (unsigned short)(kq[t] & 1023u);
    base += (int)__popcll(m);
  }
}

// Boundary-bucket emit (r14-proven): all keys < P (cnt_lt of them) plus the
// (KNN-cnt_lt) smallest-INDEX members of bucket {P <= k < P+1024}.
__device__ __forceinline__ void emit20c(const unsigned (&kq)[16], unsigned P, int cnt_lt,
                                        int lane, unsigned short* __restrict__ idx_out) {
  const unsigned long long lmask = (1ull << lane) - 1ull;
  const int need = KNN - cnt_lt;
  int base_lt = 0, base_eq = 0;
#pragma unroll
  for (int t = 0; t < 16; ++t) {
    const bool lt = (kq[t] < P);
    const bool eq = ((kq[t] - P) < 1024u);
    const unsigned long long mlt = __ballot(lt);
    const unsigned long long meq = __ballot(eq);
    if (lt) idx_out[base_lt + (int)__popcll(mlt & lmask)] = (unsigned short)(kq[t] & 1023u);
    const int erank = base_eq + (int)__popcll(meq & lmask);
    if (eq && erank < need) idx_out[cnt_lt + erank] = (unsigned short)(kq[t] & 1023u);
    base_lt += (int)__popcll(mlt);
    base_eq += (int)__popcll(meq);
  }
}

// Dual-row ballot-radix select (r12/r13-proven), bit-10 cap + early exit (r15).
__device__ __forceinline__ void select20x2(const unsigned (&k0)[16], const unsigned (&k1)[16],
    int lane, unsigned short* __restrict__ o0, unsigned short* __restrict__ o1) {
  unsigned p0 = 0u, p1 = 0u;
  bool d0 = false, d1 = false;
#pragma unroll 1
  for (int b = 31; b >= 10; --b) {
    if (!d0) {
      const unsigned cand = p0 | (1u << b);
      int cnt = 0;
#pragma unroll
      for (int t = 0; t < 16; ++t) cnt += (int)__popcll(__ballot(k0[t] < cand));
      if (cnt == KNN)      { p0 = cand - 1u; d0 = true; }   // exact set: {k <= cand-1}
      else if (cnt < KNN)  { p0 = cand; }
    }
    if (!d1) {
      const unsigned cand = p1 | (1u << b);
      int cnt = 0;
#pragma unroll
      for (int t = 0; t < 16; ++t) cnt += (int)__popcll(__ballot(k1[t] < cand));
      if (cnt == KNN)      { p1 = cand - 1u; d1 = true; }
      else if (cnt < KNN)  { p1 = cand; }
    }
    if (d0 && d1) break;
  }
  if (d0) emit20(k0, p0, lane, o0);
  else {
    int c = 0;
#pragma unroll
    for (int t = 0; t < 16; ++t) c += (int)__popcll(__ballot(k0[t] < p0));
    emit20c(k0, p0, c, lane, o0);
  }
  if (d1) emit20(k1, p1, lane, o1);
  else {
    int c = 0;
#pragma unroll
    for (int t = 0; t < 16; ++t) c += (int)__popcll(__ballot(k1[t] < p1));
    emit20c(k1, p1, c, lane, o1);
  }
}

// ---------------- weight pre-fragmentation: MFMA-ordered bf16 tables ----------------
__global__ __launch_bounds__(256) void prep_kernel(const float* __restrict__ W2, const float* __restrict__ W3,
    const float* __restrict__ W4, const float* __restrict__ Wp,
    unsigned short* __restrict__ w2b, unsigned short* __restrict__ w3b,
    unsigned short* __restrict__ w4b, unsigned short* __restrict__ wpb) {
  const int i = blockIdx.x * 256 + threadIdx.x;
  if (i < 512) {                               // W2
    const int lane = i & 63, ks = (i >> 6) & 1, nt = i >> 7;
    const int col = nt*16 + (lane & 15), k0 = ks*32 + ((lane >> 4) << 3);
#pragma unroll
    for (int e = 0; e < 8; ++e) w2b[i*8 + e] = f2bf(W2[(size_t)(k0 + e)*64 + col]);
  } else if (i < 1024) {                       // W3
    const int ii = i - 512;
    const int lane = ii & 63, ks = (ii >> 6) & 1, nt = ii >> 7;
    const int col = nt*16 + (lane & 15), k0 = ks*32 + ((lane >> 4) << 3);
#pragma unroll
    for (int e = 0; e < 8; ++e) w3b[ii*8 + e] = f2bf(W3[(size_t)(k0 + e)*64 + col]);
  } else if (i < 3072) {                       // W4
    const int ii = i - 1024;
    const int lane = ii & 63, ks = (ii >> 6) & 3, nt = ii >> 8;
    const int col = nt*16 + (lane & 15), k0 = ks*32 + ((lane >> 4) << 3);
#pragma unroll
    for (int e = 0; e < 8; ++e) w4b[ii*8 + e] = f2bf(W4[(size_t)(k0 + e)*128 + col]);
  } else if (i < 11264) {                      // Wp (hi + lo planes)
    const int ii = i - 3072;
    const int lane = ii & 63, ks = (ii >> 6) & 3, nt = ii >> 8;
    const int col = nt*16 + (lane & 15), k0 = ks*32 + ((lane >> 4) << 3);
#pragma unroll
    for (int e = 0; e < 8; ++e) {
      const float v = Wp[(size_t)(k0 + e)*512 + col];
      const unsigned short h = f2bf(v);
      wpb[ii*8 + e]         = h;
      wpb[65536 + ii*8 + e] = f2bf(v - bf2f(h));
    }
  }
}

// ---------------- kNN on 3-D coords: one wave per TWO rows ----------------
__global__ __launch_bounds__(256) void knn3_kernel(const float* __restrict__ x, unsigned short* __restrict__ idxo) {
  const int pair = blockIdx.x * 4 + (threadIdx.x >> 6);
  const int lane = threadIdx.x & 63;
  const int row0 = pair * 2;
  const int b = row0 >> 10;
  const int ia = row0 & (BN - 1), ib = ia + 1;
  const float* xb = x + (size_t)b * BN * 3;
  const float xa0 = xb[ia*3+0], xa1 = xb[ia*3+1], xa2 = xb[ia*3+2];
  const float xb0 = xb[ib*3+0], xb1 = xb[ib*3+1], xb2 = xb[ib*3+2];
  const float sqa = xa0*xa0 + xa1*xa1 + xa2*xa2;
  const float sqb = xb0*xb0 + xb1*xb1 + xb2*xb2;
  unsigned k0[16], k1[16];
#pragma unroll
  for (int t = 0; t < 16; ++t) {
    const int j = (t << 6) | lane;
    const float a0 = xb[j*3+0], a1 = xb[j*3+1], a2 = xb[j*3+2];
    const float sqj = a0*a0 + a1*a1 + a2*a2;
    const float da  = sqa + sqj - 2.0f*(xa0*a0 + xa1*a1 + xa2*a2);   // reference formula
    const float db  = sqb + sqj - 2.0f*(xb0*a0 + xb1*a1 + xb2*a2);
    k0[t] = (j == ia) ? 0xFFFFFFFFu : ((fkey(da) & 0xFFFFFC00u) | (unsigned)j);
    k1[t] = (j == ib) ? 0xFFFFFFFFu : ((fkey(db) & 0xFFFFFC00u) | (unsigned)j);
  }
  select20x2(k0, k1, lane, idxo + (size_t)row0 * KNN, idxo + (size_t)(row0 + 1) * KNN);
}

// ---------------- EdgeConv1 via MFMA; outputs ONLY bf16 hi/lo + sqnorm ----------------
// (fp32 out1 dropped: downstream consumers reconstruct x = hi+lo, error ~2^-17.)
__global__ __launch_bounds__(256) void edge1_mfma_kernel(const float* __restrict__ x, const unsigned short* __restrict__ idx,
    const float* __restrict__ W1, const float* __restrict__ B1,
    const unsigned short* __restrict__ w2b, const float* __restrict__ B2,
    const unsigned short* __restrict__ w3b, const float* __restrict__ B3,
    unsigned short* __restrict__ hib, unsigned short* __restrict__ lob,
    float* __restrict__ sqbuf) {
  __shared__ unsigned short Hs1[80*64];
  __shared__ unsigned short Hs2[80*64];
  __shared__ float part[4][4];
  const int t = threadIdx.x, lane = t & 63, w = t >> 6;
  const int node0 = blockIdx.x * 4;

  const int bcol = w*16 + (lane & 15);
  bf16x8_t Bf2[2], Bf3[2];
#pragma unroll
  for (int ks = 0; ks < 2; ++ks) {
    Bf2[ks] = *(const bf16x8_t*)&w2b[(size_t)((w*2 + ks)*64 + lane) * 8];
    Bf3[ks] = *(const bf16x8_t*)&w3b[(size_t)((w*2 + ks)*64 + lane) * 8];
  }

  float w1c[6];
#pragma unroll
  for (int c = 0; c < 6; ++c) w1c[c] = W1[c*64 + lane];
  const float b1o = B1[lane];
  for (int r = w; r < 80; r += 4) {
    const int g = (r * 205) >> 12;
    const int e = r - g*20;
    const int node = node0 + g;
    const int b = node >> 10;
    const int j = idx[(size_t)node*KNN + e];
    const float xi0 = x[(size_t)node*3+0], xi1 = x[(size_t)node*3+1], xi2 = x[(size_t)node*3+2];
    const size_t jr = ((size_t)(b*BN + j))*3;
    const float h3 = x[jr+0]-xi0, h4 = x[jr+1]-xi1, h5 = x[jr+2]-xi2;
    float z = b1o + xi0*w1c[0] + xi1*w1c[1] + xi2*w1c[2]
                  + h3*w1c[3] + h4*w1c[4] + h5*w1c[5];
    z = fmaxf(z, 0.0f);
    Hs1[r*64 + (((lane>>3) ^ (r&7))<<3) + (lane&7)] = f2bf(z);
  }
  __syncthreads();

  f32x4_t acc[5];
#pragma unroll
  for (int mt = 0; mt < 5; ++mt) acc[mt] = (f32x4_t){0,0,0,0};
#pragma unroll
  for (int ks = 0; ks < 2; ++ks) {
#pragma unroll
    for (int mt = 0; mt < 5; ++mt) {
      const int r = mt*16 + (lane & 15);
      const int chunk = ks*4 + (lane >> 4);
      const bf16x8_t a = *(const bf16x8_t*)&Hs1[r*64 + ((chunk ^ (r&7))<<3)];
      acc[mt] = __builtin_amdgcn_mfma_f32_16x16x32_bf16(a, Bf2[ks], acc[mt], 0,0,0);
    }
  }
  {
    const float b2o = B2[bcol];
    const int rbase = (lane >> 4) * 4;
#pragma unroll
    for (int mt = 0; mt < 5; ++mt) {
#pragma unroll
      for (int reg = 0; reg < 4; ++reg) {
        const int row = mt*16 + rbase + reg;
        const float v = fmaxf(acc[mt][reg] + b2o, 0.0f);
        Hs2[row*64 + (((bcol>>3) ^ (row&7))<<3) + (bcol&7)] = f2bf(v);
      }
    }
  }
  __syncthreads();

#pragma unroll
  for (int mt = 0; mt < 5; ++mt) acc[mt] = (f32x4_t){0,0,0,0};
#pragma unroll
  for (int ks = 0; ks < 2; ++ks) {
#pragma unroll
    for (int mt = 0; mt < 5; ++mt) {
      const int r = mt*16 + (lane & 15);
      const int chunk = ks*4 + (lane >> 4);
      const bf16x8_t a = *(const bf16x8_t*)&Hs2[r*64 + ((chunk ^ (r&7))<<3)];
      acc[mt] = __builtin_amdgcn_mfma_f32_16x16x32_bf16(a, Bf3[ks], acc[mt], 0,0,0);
    }
  }

  {
    const float b3o = B3[bcol];
    const int rbase = (lane >> 4) * 4;
    float nm0 = 0.0f, nm1 = 0.0f, nm2 = 0.0f, nm3 = 0.0f;
#pragma unroll
    for (int mt = 0; mt < 5; ++mt) {
#pragma unroll
      for (int reg = 0; reg < 4; ++reg) {
        const int r = mt*16 + rbase + reg;
        const int g = (r * 205) >> 12;
        const float v = fmaxf(acc[mt][reg] + b3o, 0.0f);
        nm0 = (g == 0) ? fmaxf(nm0, v) : nm0;
        nm1 = (g == 1) ? fmaxf(nm1, v) : nm1;
        nm2 = (g == 2) ? fmaxf(nm2, v) : nm2;
        nm3 = (g == 3) ? fmaxf(nm3, v) : nm3;
      }
    }
#pragma unroll
    for (int off = 16; off <= 32; off <<= 1) {
      nm0 = fmaxf(nm0, __shfl_xor(nm0, off, 64));
      nm1 = fmaxf(nm1, __shfl_xor(nm1, off, 64));
      nm2 = fmaxf(nm2, __shfl_xor(nm2, off, 64));
      nm3 = fmaxf(nm3, __shfl_xor(nm3, off, 64));
    }
    const int gq = lane >> 4;
    const float m = (gq == 0) ? nm0 : (gq == 1) ? nm1 : (gq == 2) ? nm2 : nm3;
    const int node = node0 + gq;
    const unsigned short h = f2bf(m);
    hib[(size_t)node*64 + bcol] = h;
    lob[(size_t)node*64 + bcol] = f2bf(m - bf2f(h));
    float s = m * m;
#pragma unroll
    for (int off = 1; off <= 8; off <<= 1) s += __shfl_xor(s, off, 64);
    if ((lane & 15) == 0) part[gq][w] = s;
  }
  __syncthreads();
  if (t < 4) sqbuf[node0 + t] = part[t][0] + part[t][1] + part[t][2] + part[t][3];
}

// ---------------- FUSED kNN-64 + EdgeConv2 ----------------
// Per block (512 thr, 8 waves, 16 nodes):
//  P1: bf16x3 MFMA distances -> packed keys in Dmat (r13-proven, 126 µs alone)
//  P2: dual-row radix select -> neighbor idx in LDS (no global idx2 round-trip)
//  P3: EdgeConv2 for the same 16 nodes, two 8-node halves, REUSING Dmat as Hs
//      (40 KB <= 64 KB). Gather reconstructs x = hi+lo (xi's bf16 IS hib's bytes).
// Rationale: knn64 alone sits at VALU 22% / MFMA 4% (latency-bound select);
// fusing edge2's MFMA/gather gives co-resident blocks heterogeneous phases to
// fill those idle slots.
__global__ __launch_bounds__(512) void knn64edge2_kernel(
    const unsigned short* __restrict__ hi, const unsigned short* __restrict__ lo,
    const float* __restrict__ sq, const unsigned short* __restrict__ w4b,
    const float* __restrict__ B4,
    unsigned short* __restrict__ o2hi, unsigned short* __restrict__ o2lo) {
  __shared__ unsigned Dmat[16 * 1024];              // 64 KiB; aliased as Hs in P3
  __shared__ unsigned short idx_sh[16][KNN];        // 640 B
  unsigned short* Hs = (unsigned short*)Dmat;       // bf16 [160*128] = 40 KiB
  const int t = threadIdx.x, lane = t & 63, w = t >> 6;   // w in [0,8)
  const int i0  = blockIdx.x * 16;
  const int b   = i0 >> 10;
  const int i0l = i0 & (BN - 1);

  // ---- P1: distances (verbatim r13/r15 structure) ----
  {
    const size_t arow = (size_t)(i0 + (lane & 15)) * 64;
    const int    koff = (lane >> 4) * 8;
    bf16x8_t Ahi[2], Alo[2];
#pragma unroll
    for (int ks = 0; ks < 2; ++ks) {
      Ahi[ks] = *(const bf16x8_t*)&hi[arow + ks*32 + koff];
      Alo[ks] = *(const bf16x8_t*)&lo[arow + ks*32 + koff];
    }
    f32x4_t acc[8];
#pragma unroll
    for (int nt = 0; nt < 8; ++nt) {
      const int jl = (8*w + nt)*16 + (lane & 15);
      const size_t jrow = ((size_t)(b << 10) + jl) * 64;
      const bf16x8_t Bhi0 = *(const bf16x8_t*)&hi[jrow + koff];
      const bf16x8_t Bhi1 = *(const bf16x8_t*)&hi[jrow + 32 + koff];
      const bf16x8_t Blo0 = *(const bf16x8_t*)&lo[jrow + koff];
      const bf16x8_t Blo1 = *(const bf16x8_t*)&lo[jrow + 32 + koff];
      f32x4_t a = (f32x4_t){0,0,0,0};
      a = __builtin_amdgcn_mfma_f32_16x16x32_bf16(Ahi[0], Bhi0, a, 0,0,0);
      a = __builtin_amdgcn_mfma_f32_16x16x32_bf16(Ahi[1], Bhi1, a, 0,0,0);
      a = __builtin_amdgcn_mfma_f32_16x16x32_bf16(Ahi[0], Blo0, a, 0,0,0);
      a = __builtin_amdgcn_mfma_f32_16x16x32_bf16(Ahi[1], Blo1, a, 0,0,0);
      a = __builtin_amdgcn_mfma_f32_16x16x32_bf16(Alo[0], Bhi0, a, 0,0,0);
      a = __builtin_amdgcn_mfma_f32_16x16x32_bf16(Alo[1], Bhi1, a, 0,0,0);
      acc[nt] = a;
    }
    const int rbase = (lane >> 4) * 4;
    float sqr[4];
#pragma unroll
    for (int r = 0; r < 4; ++r) sqr[r] = sq[i0 + rbase + r];
#pragma unroll
    for (int nt = 0; nt < 8; ++nt) {
      const int jl = (8*w + nt)*16 + (lane & 15);
      const float sqj = sq[(b << 10) + jl];
#pragma unroll
      for (int r = 0; r < 4; ++r) {
        const float d = sqr[r] + sqj - 2.0f * acc[nt][r];
        const unsigned kq = (jl == i0l + rbase + r) ? 0xFFFFFFFFu
                          : ((fkey(d) & 0xFFFFFC00u) | (unsigned)jl);
        Dmat[(rbase + r)*1024 + jl] = kq;
      }
    }
  }
  __syncthreads();

  // ---- P2: select rows {2w, 2w+1} -> idx_sh ----
  {
    const int r0 = 2*w, r1 = 2*w + 1;
    unsigned k0[16], k1[16];
#pragma unroll
    for (int tt = 0; tt < 16; ++tt) {
      k0[tt] = Dmat[r0*1024 + tt*64 + lane];
      k1[tt] = Dmat[r1*1024 + tt*64 + lane];
    }
    select20x2(k0, k1, lane, &idx_sh[r0][0], &idx_sh[r1][0]);
  }
  __syncthreads();   // all Dmat reads done; idx_sh visible; Hs may now overwrite Dmat

  // ---- P3: EdgeConv2, two 8-node halves (wave w owns node h*8+w and n-tile w) ----
  bf16x8_t Bfrag[4];
#pragma unroll
  for (int ks = 0; ks < 4; ++ks)
    Bfrag[ks] = *(const bf16x8_t*)&w4b[(size_t)((w*4 + ks)*64 + lane) * 8];
  const float bb = B4[w*16 + (lane & 15)];
  const int cq = (lane & 15) * 4;
  const int ch1 = cq >> 3, ch2 = 8 + (cq >> 3), sub = cq & 4;
  const int rbase = (lane >> 4) * 4;

#pragma unroll 1
  for (int h = 0; h < 2; ++h) {
    const int mynode = i0 + h*8 + w;
    const size_t noff = (size_t)mynode*64 + cq;
    const ushort4 hxi = *(const ushort4*)&hi[noff];   // xi bf16 == hib bytes (exact)
    const ushort4 lxi = *(const ushort4*)&lo[noff];
    const float xi0 = bf2f(hxi.x) + bf2f(lxi.x);
    const float xi1 = bf2f(hxi.y) + bf2f(lxi.y);
    const float xi2 = bf2f(hxi.z) + bf2f(lxi.z);
    const float xi3 = bf2f(hxi.w) + bf2f(lxi.w);
#pragma unroll
    for (int i = 0; i < 5; ++i) {
      const int e = i*4 + (lane >> 4);
      const int j = idx_sh[h*8 + w][e];
      const size_t joff = ((size_t)(b*BN + j))*64 + cq;
      const ushort4 hxj = *(const ushort4*)&hi[joff];
      const ushort4 lxj = *(const ushort4*)&lo[joff];
      ushort4 hdf;
      hdf.x = f2bf(bf2f(hxj.x) + bf2f(lxj.x) - xi0);
      hdf.y = f2bf(bf2f(hxj.y) + bf2f(lxj.y) - xi1);
      hdf.z = f2bf(bf2f(hxj.z) + bf2f(lxj.z) - xi2);
      hdf.w = f2bf(bf2f(hxj.w) + bf2f(lxj.w) - xi3);
      const int r = w*20 + e;
      *(ushort4*)&Hs[r*128 + ((ch1 ^ (r&7))<<3) + sub] = hxi;
      *(ushort4*)&Hs[r*128 + ((ch2 ^ (r&7))<<3) + sub] = hdf;
    }
    __syncthreads();                                  // Hs complete

    f32x4_t acc2[10];
#pragma unroll
    for (int mt = 0; mt < 10; ++mt) acc2[mt] = (f32x4_t){0,0,0,0};
#pragma unroll
    for (int ks = 0; ks < 4; ++ks) {
#pragma unroll
      for (int mt = 0; mt < 10; ++mt) {
        const int r = mt*16 + (lane & 15);
        const int chunk = ks*4 + (lane >> 4);
        const bf16x8_t a = *(const bf16x8_t*)&Hs[r*128 + ((chunk ^ (r&7))<<3)];
        acc2[mt] = __builtin_amdgcn_mfma_f32_16x16x32_bf16(a, Bfrag[ks], acc2[mt], 0,0,0);
      }
    }

    // epilogue (r13 constexpr two-candidate form, single n-tile)
    float nm[8];
#pragma unroll
    for (int g = 0; g < 8; ++g) nm[g] = 0.0f;
#pragma unroll
    for (int mt = 0; mt < 10; ++mt) {
#pragma unroll
      for (int reg = 0; reg < 4; ++reg) {
        const int base = mt*16 + reg;          // compile-time after unroll
        const int glo = base / 20, ghi = (base + 12) / 20;
        const int r = base + rbase;
        const float v = fmaxf(acc2[mt][reg] + bb, 0.0f);
        if (glo == ghi) {
          nm[glo] = fmaxf(nm[glo], v);
        } else {
          const bool hi2 = (r >= ghi*20);
          nm[glo] = hi2 ? nm[glo] : fmaxf(nm[glo], v);
          nm[ghi] = hi2 ? fmaxf(nm[ghi], v) : nm[ghi];
        }
      }
    }
#pragma unroll
    for (int off = 16; off <= 32; off <<= 1)
#pragma unroll
      for (int g = 0; g < 8; ++g) nm[g] = fmaxf(nm[g], __shfl_xor(nm[g], off, 64));
    const int gq = lane >> 4;
#pragma unroll
    for (int g = 0; g < 8; ++g) {
      if ((g & 3) == gq) {
        const float m = nm[g];
        const size_t o = (size_t)(i0 + h*8 + g)*128 + w*16 + (lane & 15);
        const unsigned short hh = f2bf(m);
        o2hi[o] = hh;
        o2lo[o] = f2bf(m - bf2f(hh));
      }
    }
    __syncthreads();                                  // Hs reads done before next gather
  }
}

// ---------------- pool: 128->512 via bf16x3 MFMA, fused relu+max, atomicMax ----------------
__global__ __launch_bounds__(512) void pool_mfma_kernel(const unsigned short* __restrict__ o2hi,
    const unsigned short* __restrict__ o2lo, const unsigned short* __restrict__ wpb,
    const float* __restrict__ bp, float* __restrict__ pooled) {
  const int t = threadIdx.x, lane = t & 63, w = t >> 6;    // 8 waves
  const int b = blockIdx.x >> 3, chunk = blockIdx.x & 7;
  const int row0 = b*BN + chunk*128;
  const int koff = (lane >> 4) * 8;
  bf16x8_t Bhi[4][4], Blo[4][4];
#pragma unroll
  for (int q = 0; q < 4; ++q)
#pragma unroll
    for (int ks = 0; ks < 4; ++ks) {
      const int nt = w*4 + q;
      Bhi[q][ks] = *(const bf16x8_t*)&wpb[(size_t)((nt*4 + ks)*64 + lane) * 8];
      Blo[q][ks] = *(const bf16x8_t*)&wpb[65536 + (size_t)((nt*4 + ks)*64 + lane) * 8];
    }
  float colmax[4] = {-finf(), -finf(), -finf(), -finf()};
#pragma unroll 2
  for (int mt = 0; mt < 8; ++mt) {
    const size_t ar = (size_t)(row0 + mt*16 + (lane & 15)) * 128;
    bf16x8_t Ahi[4], Alo[4];
#pragma unroll
    for (int ks = 0; ks < 4; ++ks) {
      Ahi[ks] = *(const bf16x8_t*)&o2hi[ar + ks*32 + koff];
      Alo[ks] = *(const bf16x8_t*)&o2lo[ar + ks*32 + koff];
    }
#pragma unroll
    for (int q = 0; q < 4; ++q) {
      f32x4_t a = (f32x4_t){0,0,0,0};
#pragma unroll
      for (int ks = 0; ks < 4; ++ks) {
        a = __builtin_amdgcn_mfma_f32_16x16x32_bf16(Ahi[ks], Bhi[q][ks], a, 0,0,0);
        a = __builtin_amdgcn_mfma_f32_16x16x32_bf16(Ahi[ks], Blo[q][ks], a, 0,0,0);
        a = __builtin_amdgcn_mfma_f32_16x16x32_bf16(Alo[ks], Bhi[q][ks], a, 0,0,0);
      }
#pragma unroll
      for (int reg = 0; reg < 4; ++reg) colmax[q] = fmaxf(colmax[q], a[reg]);
    }
  }
#pragma unroll
  for (int off = 16; off <= 32; off <<= 1)
#pragma unroll
    for (int q = 0; q < 4; ++q) colmax[q] = fmaxf(colmax[q], __shfl_xor(colmax[q], off, 64));
  if (lane < 16) {
#pragma unroll
    for (int q = 0; q < 4; ++q) {
      const int col = (w*4 + q)*16 + lane;
      const float m = fmaxf(colmax[q] + bp[col], 0.0f);   // relu(max+b) == max(relu(z))
      atomicMax((int*)(pooled + (size_t)b*512 + col), __float_as_int(m));
    }
  }
}

// ---------------- classifier head 512->256(relu)->40 ----------------
__global__ __launch_bounds__(256) void head_kernel(const float* __restrict__ pooled,
    const float* __restrict__ Wt1, const float* __restrict__ bt1,
    const float* __restrict__ Wt2, const float* __restrict__ bt2,
    float* __restrict__ out) {
  __shared__ float psh[512];
  __shared__ float h1sh[256];
  const int t = threadIdx.x, b = blockIdx.x;
  psh[t]       = pooled[(size_t)b*512 + t];
  psh[t + 256] = pooled[(size_t)b*512 + t + 256];
  __syncthreads();
  float z = bt1[t];
  for (int j = 0; j < 512; ++j) z += psh[j] * Wt1[(size_t)j*256 + t];
  h1sh[t] = fmaxf(z, 0.0f);
  __syncthreads();
  if (t < 40) {
    float z2 = bt2[t];
    for (int j = 0; j < 256; ++j) z2 += h1sh[j] * Wt2[(size_t)j*40 + t];
    out[(size_t)b*40 + t] = z2;
  }
}

extern "C" void kernel_launch(void* const* d_in, const int* in_sizes, int n_in,
                              void* d_out, int out_size, void* d_ws, size_t ws_size,
                              hipStream_t stream) {
  const float* x   = (const float*)d_in[0];
  // d_in[1] = batch indices (unused: equal-sized clouds)
  const float* W1  = (const float*)d_in[2];
  const float* B1  = (const float*)d_in[3];
  const float* W2  = (const float*)d_in[4];
  const float* B2  = (const float*)d_in[5];
  const float* W3  = (const float*)d_in[6];
  const float* B3  = (const float*)d_in[7];
  const float* W4  = (const float*)d_in[8];
  const float* B4  = (const float*)d_in[9];
  const float* Wp  = (const float*)d_in[10];
  const float* bp  = (const float*)d_in[11];
  const float* Wt1 = (const float*)d_in[12];
  const float* bt1 = (const float*)d_in[13];
  const float* Wt2 = (const float*)d_in[14];
  const float* bt2 = (const float*)d_in[15];
  float* out = (float*)d_out;

  // workspace layout (bytes): total 26,984,448 <= proven-available 28,295,168
  // (fp32 out1 dropped; o2hi/o2lo now DISJOINT from hib/lob — the fused kernel
  //  reads hib/lob while writing o2, so the old aliasing would race.)
  char* ws = (char*)d_ws;
  const size_t OFF_SQ     = 0;            // 32768*4            = 131072
  const size_t OFF_IDX1   = 131072;       // 32768*20*2 (u16)   = 1310720
  const size_t OFF_HIB    = 1441792;      // 32768*64*2         = 4194304
  const size_t OFF_LOB    = 5636096;      // 4194304
  const size_t OFF_O2HI   = 9830400;      // 32768*128*2        = 8388608
  const size_t OFF_O2LO   = 18219008;     // 8388608
  const size_t OFF_POOLED = 26607616;     // 32*512*4           = 65536
  const size_t OFF_W2B    = 26673152;     // 8192
  const size_t OFF_W3B    = 26681344;     // 8192
  const size_t OFF_W4B    = 26689536;     // 32768
  const size_t OFF_WPB    = 26722304;     // 262144
  const size_t WS_NEEDED  = 26984448;
  if (ws_size < WS_NEEDED) return;        // fail loudly (validation will catch it)

  float*          sqbuf  = (float*)(ws + OFF_SQ);
  unsigned short* idx1   = (unsigned short*)(ws + OFF_IDX1);
  unsigned short* hib    = (unsigned short*)(ws + OFF_HIB);
  unsigned short* lob    = (unsigned short*)(ws + OFF_LOB);
  unsigned short* o2hi   = (unsigned short*)(ws + OFF_O2HI);
  unsigned short* o2lo   = (unsigned short*)(ws + OFF_O2LO);
  float*          pooled = (float*)(ws + OFF_POOLED);
  unsigned short* w2b    = (unsigned short*)(ws + OFF_W2B);
  unsigned short* w3b    = (unsigned short*)(ws + OFF_W3B);
  unsigned short* w4b    = (unsigned short*)(ws + OFF_W4B);
  unsigned short* wpb    = (unsigned short*)(ws + OFF_WPB);

  prep_kernel       <<<44,          256, 0, stream>>>(W2, W3, W4, Wp, w2b, w3b, w4b, wpb);
  knn3_kernel       <<<NROWS/8,     256, 0, stream>>>(x, idx1);
  edge1_mfma_kernel <<<NROWS/4,     256, 0, stream>>>(x, idx1, W1, B1, w2b, B2, w3b, B3,
                                                      hib, lob, sqbuf);
  knn64edge2_kernel <<<NROWS/16,    512, 0, stream>>>(hib, lob, sqbuf, w4b, B4, o2hi, o2lo);
  hipMemsetAsync(pooled, 0, NB*512*sizeof(float), stream);
  pool_mfma_kernel  <<<NB*8,        512, 0, stream>>>(o2hi, o2lo, wpb, bp, pooled);
  head_kernel       <<<NB,          256, 0, stream>>>(pooled, Wt1, bt1, Wt2, bt2, out);
}